// Round 11
// baseline (138.376 us; speedup 1.0000x reference)
//
#include <hip/hip_runtime.h>
#include <hip/hip_bf16.h>

#define CIN 128
#define COUT 256
#define H 56
#define W 56
#define OH 54
#define OW 54

typedef __attribute__((ext_vector_type(8))) short short8;
typedef __attribute__((ext_vector_type(4))) float floatx4;

typedef __attribute__((address_space(3))) unsigned int  lds_u32;
typedef const __attribute__((address_space(1))) unsigned int glb_u32;

static __device__ __forceinline__ unsigned short f2bf(float f) {
  unsigned int u = __builtin_bit_cast(unsigned int, f);
  u += 0x7fffu + ((u >> 16) & 1u);   // RNE
  return (unsigned short)(u >> 16);
}

// ---------- prepass 1: w[co][ci][kh][kw] f32 -> w3[s][g][co][8] bf16 ----------
// s = kh*12 + ch*3 + kw (flat k-step), ci = (ch*4+g)*8 + j. Each step's A-slice
// is a CONTIGUOUS 16 KB block -> DMA-able with global_load_lds.
__global__ void repack_w(const float* __restrict__ w, unsigned short* __restrict__ w3) {
  int idx = blockIdx.x * 256 + threadIdx.x;
  if (idx >= COUT * CIN * 9) return;
  int kw = idx % 3, t1 = idx / 3;
  int kh = t1 % 3, t2 = t1 / 3;
  int ci = t2 % CIN;
  int co = t2 / CIN;
  int c8 = ci >> 3, j = ci & 7;
  int ch = c8 >> 2, g = c8 & 3;
  int s = kh * 12 + ch * 3 + kw;
  w3[(((s * 4 + g) * COUT + co) * 8) + j] = f2bf(w[idx]);
}

// ---------- prepass 2 (LDS transpose, coalesced both sides) ----------
// x NCHW f32 -> xb[n][h][g'] bf16, g' = iw*16 + (c16 ^ (iw&7)).
__global__ __launch_bounds__(256) void repack_x(const float* __restrict__ x,
                                                unsigned short* __restrict__ xb) {
  __shared__ float xt[56][129];
  const int h = blockIdx.x;       // 0..55
  const int n = blockIdx.y;       // 0..31
  const float* src = x + (size_t)n * CIN * (H * W) + h * W;
  #pragma unroll
  for (int r = 0; r < 28; ++r) {
    int idx = r * 256 + threadIdx.x;
    int ci = idx / 56, iw = idx % 56;
    xt[iw][ci] = src[ci * (H * W) + iw];
  }
  __syncthreads();
  unsigned short* dst = xb + ((size_t)n * H + h) * 896 * 8;
  #pragma unroll
  for (int r = 0; r < 4; ++r) {
    int g = r * 256 + threadIdx.x;
    if (g < 896) {
      int iw = g >> 4, c16 = g & 15;
      short8 v;
      #pragma unroll
      for (int j = 0; j < 8; ++j)
        v[j] = (short)f2bf(xt[iw][c16 * 8 + j]);
      int gp = iw * 16 + (c16 ^ (iw & 7));
      *reinterpret_cast<short8*>(&dst[gp * 8]) = v;
    }
  }
}

// ---------- main conv: T3/T4 structure ----------
// 8 waves = 4 co-groups x 2 rows. A-slices (16 KB/k-step) DMA'd into a 3-deep
// LDS ring 2 tiles ahead; per-tile sync = counted s_waitcnt vmcnt(2) + RAW
// s_barrier (never a drain-to-0 until the epilogue).
__global__ __launch_bounds__(512, 2) void conv4(
    const unsigned short* __restrict__ xb, const unsigned short* __restrict__ w3,
    const float* __restrict__ bias, float* __restrict__ out) {
  __shared__ alignas(16) unsigned short xs[3744 * 8];        // 59,904 B
  __shared__ alignas(16) unsigned short abuf[3][1024 * 8];   // 49,152 B

  // XCD-bijective swizzle: 864 % 8 == 0
  const int f = blockIdx.x;
  const int swz = (f & 7) * 108 + (f >> 3);
  const int ohp = swz % 27;
  const int n   = swz / 27;
  const int oh0 = ohp * 2;
  const int tid = threadIdx.x;
  const int wid  = tid >> 6;
  const int lane = tid & 63;

  const int wm   = wid >> 1;       // co group (0..3)
  const int wn   = wid & 1;        // output row within the pair
  const int l16  = lane & 15;
  const int cig  = lane >> 4;      // 0..3
  const int co_base = wm * 64;
  const int oh = oh0 + wn;
  const int rowd = cig * 4;

  // ---- bias preload (keeps the K-loop's vmem stream DMA-only) ----
  float bv[4][4];
  #pragma unroll
  for (int m = 0; m < 4; ++m)
    #pragma unroll
    for (int reg = 0; reg < 4; ++reg)
      bv[m][reg] = bias[co_base + m * 16 + rowd + reg];

  // ---- stage x rows (7 wave-issues per wave) ----
  {
    const unsigned short* src = xb + ((size_t)n * H + oh0) * 896 * 8;
    #pragma unroll
    for (int i = 0; i < 7; ++i) {
      int idx = (wid * 7 + i) * 64;
      __builtin_amdgcn_global_load_lds(
          (glb_u32*)(src + (size_t)(idx + lane) * 8),
          (lds_u32*)(&xs[idx * 8]), 16, 0, 0);
    }
  }

  // A-slice DMA: 16 KB = 16 wave-issues (2 per wave). Uniform LDS base + lane*16.
#define ASTAGE(t)                                                               \
  {                                                                             \
    const unsigned short* asrc_ = w3 + (size_t)(t) * 8192;                      \
    unsigned short* adst_ = &abuf[(t) % 3][0];                                  \
    const int b0_ = (wid * 2) * 64;                                             \
    const int b1_ = (wid * 2 + 1) * 64;                                         \
    __builtin_amdgcn_global_load_lds((glb_u32*)(asrc_ + (size_t)(b0_ + lane) * 8), \
                                     (lds_u32*)(adst_ + (size_t)b0_ * 8), 16, 0, 0); \
    __builtin_amdgcn_global_load_lds((glb_u32*)(asrc_ + (size_t)(b1_ + lane) * 8), \
                                     (lds_u32*)(adst_ + (size_t)b1_ * 8), 16, 0, 0); \
  }

  ASTAGE(0);
  ASTAGE(1);
  // in flight: bias(16) + xs(7) + A0(2) + A1(2); wait until only A1 remains
  asm volatile("s_waitcnt vmcnt(2)" ::: "memory");
  __builtin_amdgcn_s_barrier();
  __builtin_amdgcn_sched_barrier(0);

  // per-wave B addressing
  const int bwn = wn * 896 * 8;
  int ib[3], x7[3];
  #pragma unroll
  for (int kw = 0; kw < 3; ++kw) {
    ib[kw] = (l16 + kw) * 128;
    x7[kw] = (l16 + kw) & 7;
  }
  const int aoff = (cig * 256 + co_base + l16) * 8;

  floatx4 acc[4][4];
  #pragma unroll
  for (int m = 0; m < 4; ++m)
    #pragma unroll
    for (int nr = 0; nr < 4; ++nr)
      acc[m][nr] = (floatx4){0.f, 0.f, 0.f, 0.f};

  #pragma unroll
  for (int t = 0; t < 36; ++t) {
    // issue DMA for tile t+2 (slot (t+2)%3 was fully read at tile t-1)
    if (t + 2 < 36) ASTAGE(t + 2);

    const int kh = t / 12, ch = (t / 3) & 3, kw = t % 3;
    short8 a[4], b[4];
    const unsigned short* ab = &abuf[t % 3][aoff];
    a[0] = *reinterpret_cast<const short8*>(ab);
    a[1] = *reinterpret_cast<const short8*>(ab + 128);
    a[2] = *reinterpret_cast<const short8*>(ab + 256);
    a[3] = *reinterpret_cast<const short8*>(ab + 384);
    const int c16x = (ch * 4 + cig) ^ x7[kw];
    const int boff = bwn + kh * (896 * 8) + ib[kw] + c16x * 8;
    b[0] = *reinterpret_cast<const short8*>(&xs[boff]);
    b[1] = *reinterpret_cast<const short8*>(&xs[boff + 2048]);
    b[2] = *reinterpret_cast<const short8*>(&xs[boff + 4096]);
    b[3] = *reinterpret_cast<const short8*>(&xs[boff + 6144]);

    __builtin_amdgcn_sched_barrier(0);
    __builtin_amdgcn_s_setprio(1);
    #pragma unroll
    for (int m = 0; m < 4; ++m)
      #pragma unroll
      for (int nr = 0; nr < 4; ++nr)
        acc[m][nr] = __builtin_amdgcn_mfma_f32_16x16x32_bf16(a[m], b[nr], acc[m][nr], 0, 0, 0);
    __builtin_amdgcn_s_setprio(0);
    __builtin_amdgcn_sched_barrier(0);

    // counted wait: tile t+1's DMA landed; t+2's may stay in flight
    if (t < 34)       asm volatile("s_waitcnt vmcnt(2)" ::: "memory");
    else if (t == 34) asm volatile("s_waitcnt vmcnt(0)" ::: "memory");
    if (t < 35) {
      __builtin_amdgcn_s_barrier();
      __builtin_amdgcn_sched_barrier(0);
    }
  }
#undef ASTAGE

  // ---- epilogue: C/D layout col=lane&15, row=(lane>>4)*4+reg ----
  #pragma unroll
  for (int m = 0; m < 4; ++m) {
    #pragma unroll
    for (int reg = 0; reg < 4; ++reg) {
      int co = co_base + m * 16 + rowd + reg;
      float* op = out + (((size_t)n * COUT + co) * OH + oh) * OW;
      #pragma unroll
      for (int nr = 0; nr < 4; ++nr) {
        int ow = nr * 16 + l16;
        if (ow < OW) op[ow] = acc[m][nr][reg] + bv[m][reg];
      }
    }
  }
}

// ================== fallback path (ws too small): round-2 kernel ==================
#define CSTR 136
#define IWP 66

__global__ void repack_w_fb(const float* __restrict__ w, unsigned short* __restrict__ w2) {
  int idx = blockIdx.x * 256 + threadIdx.x;
  if (idx >= COUT * CIN * 9) return;
  int kw = idx % 3, t1 = idx / 3;
  int kh = t1 % 3, t2 = t1 / 3;
  int ci = t2 % CIN;
  int co = t2 / CIN;
  int c8 = ci >> 3, j = ci & 7;
  w2[((((kh * 3 + kw) * 16 + c8) * COUT + co) * 8) + j] = f2bf(w[idx]);
}

__global__ __launch_bounds__(512, 4) void conv_fb(
    const float* __restrict__ x, const unsigned short* __restrict__ w2,
    const float* __restrict__ bias, float* __restrict__ out) {
  __shared__ alignas(16) unsigned short xsf[4 * IWP * CSTR];

  const int ohp = blockIdx.x;
  const int n   = blockIdx.y;
  const int oh0 = ohp * 2;
  const int tid = threadIdx.x;

  {
    short8 zz = {0, 0, 0, 0, 0, 0, 0, 0};
    for (int i = tid; i < 4 * 10 * 17; i += 512) {
      int r = i / 170, rem = i % 170;
      int iw = 56 + rem / 17, g = rem % 17;
      *reinterpret_cast<short8*>(&xsf[(r * IWP + iw) * CSTR + g * 8]) = zz;
    }
  }
  for (int s = tid; s < 3584; s += 512) {
    int iw = s % 56;
    int t  = s / 56;
    int c8 = t & 15, r = t >> 4;
    const float* xp = x + (size_t)n * CIN * (H * W) + (oh0 + r) * W + iw;
    short8 v;
    #pragma unroll
    for (int j = 0; j < 8; ++j)
      v[j] = (short)f2bf(xp[(size_t)(c8 * 8 + j) * (H * W)]);
    *reinterpret_cast<short8*>(&xsf[(r * IWP + iw) * CSTR + c8 * 8]) = v;
  }
  __syncthreads();

  const int wid  = tid >> 6;
  const int lane = tid & 63;
  const int wm   = wid >> 1;
  const int wn   = wid & 1;
  const int l16  = lane & 15;
  const int cig  = lane >> 4;

  const int co_base = wm * 64;
  const int oh = oh0 + wn;

  floatx4 acc[4][4];
  #pragma unroll
  for (int m = 0; m < 4; ++m)
    #pragma unroll
    for (int nr = 0; nr < 4; ++nr)
      acc[m][nr] = (floatx4){0.f, 0.f, 0.f, 0.f};

  for (int kh = 0; kh < 3; ++kh) {
    const int row = wn + kh;
    #pragma unroll
    for (int ch = 0; ch < 4; ++ch) {
      const int bbase = (row * IWP + l16) * CSTR + ch * 32 + cig * 8;
      #pragma unroll
      for (int kw = 0; kw < 3; ++kw) {
        const unsigned short* wp =
            w2 + ((size_t)(((kh * 3 + kw) * 16 + (ch * 4 + cig)) * COUT + co_base + l16)) * 8;
        short8 a[4];
        #pragma unroll
        for (int m = 0; m < 4; ++m)
          a[m] = *reinterpret_cast<const short8*>(wp + m * 16 * 8);
        short8 b[4];
        #pragma unroll
        for (int nr = 0; nr < 4; ++nr)
          b[nr] = *reinterpret_cast<const short8*>(&xsf[bbase + (nr * 16 + kw) * CSTR]);
        #pragma unroll
        for (int m = 0; m < 4; ++m)
          #pragma unroll
          for (int nr = 0; nr < 4; ++nr)
            acc[m][nr] = __builtin_amdgcn_mfma_f32_16x16x32_bf16(a[m], b[nr], acc[m][nr], 0, 0, 0);
      }
    }
  }

  const int rowd = cig * 4;
  #pragma unroll
  for (int m = 0; m < 4; ++m) {
    #pragma unroll
    for (int reg = 0; reg < 4; ++reg) {
      int co = co_base + m * 16 + rowd + reg;
      float bvv = bias[co];
      float* op = out + (((size_t)n * COUT + co) * OH + oh) * OW;
      #pragma unroll
      for (int nr = 0; nr < 4; ++nr) {
        int ow = nr * 16 + l16;
        if (ow < OW) op[ow] = acc[m][nr][reg] + bvv;
      }
    }
  }
}

extern "C" void kernel_launch(void* const* d_in, const int* in_sizes, int n_in,
                              void* d_out, int out_size, void* d_ws, size_t ws_size,
                              hipStream_t stream) {
  (void)in_sizes; (void)n_in; (void)out_size;
  const float* x    = (const float*)d_in[0];
  const float* w    = (const float*)d_in[1];
  const float* bias = (const float*)d_in[2];
  float* out = (float*)d_out;

  const size_t W3_BYTES = (size_t)36 * 4 * COUT * 8 * 2;            // 589,824
  const size_t XB_BYTES = (size_t)32 * H * 896 * 8 * 2;             // 25,690,112
  unsigned short* wrep = (unsigned short*)d_ws;

  if (ws_size >= W3_BYTES + XB_BYTES) {
    unsigned short* xbuf = (unsigned short*)((char*)d_ws + W3_BYTES);
    repack_w<<<dim3((COUT * CIN * 9 + 255) / 256), dim3(256), 0, stream>>>(w, wrep);
    repack_x<<<dim3(56, 32), dim3(256), 0, stream>>>(x, xbuf);
    conv4<<<dim3(864), dim3(512), 0, stream>>>(xbuf, wrep, bias, out);
  } else {
    repack_w_fb<<<dim3((COUT * CIN * 9 + 255) / 256), dim3(256), 0, stream>>>(w, wrep);
    conv_fb<<<dim3(27, 32), dim3(512), 0, stream>>>(x, wrep, bias, out);
  }
}

// Round 12
// 113.380 us; speedup vs baseline: 1.2205x; 1.2205x over previous
//
#include <hip/hip_runtime.h>
#include <hip/hip_bf16.h>

#define CIN 128
#define COUT 256
#define H 56
#define W 56
#define OH 54
#define OW 54

typedef __attribute__((ext_vector_type(8))) short short8;
typedef __attribute__((ext_vector_type(4))) float floatx4;

typedef __attribute__((address_space(3))) unsigned int  lds_u32;
typedef const __attribute__((address_space(1))) unsigned int glb_u32;

static __device__ __forceinline__ unsigned short f2bf(float f) {
  unsigned int u = __builtin_bit_cast(unsigned int, f);
  u += 0x7fffu + ((u >> 16) & 1u);   // RNE
  return (unsigned short)(u >> 16);
}

// ---------- prepass 1: w[co][ci][kh][kw] f32 -> w3[s][g][co][8] bf16 ----------
// s = kh*12 + ch*3 + kw (flat k-step), ci = (ch*4+g)*8 + j. Per (s,g,co-quarter)
// the 1 KB chunk is contiguous -> one global_load_lds wave-issue.
__global__ void repack_w(const float* __restrict__ w, unsigned short* __restrict__ w3) {
  int idx = blockIdx.x * 256 + threadIdx.x;
  if (idx >= COUT * CIN * 9) return;
  int kw = idx % 3, t1 = idx / 3;
  int kh = t1 % 3, t2 = t1 / 3;
  int ci = t2 % CIN;
  int co = t2 / CIN;
  int c8 = ci >> 3, j = ci & 7;
  int ch = c8 >> 2, g = c8 & 3;
  int s = kh * 12 + ch * 3 + kw;
  w3[(((s * 4 + g) * COUT + co) * 8) + j] = f2bf(w[idx]);
}

// ---------- prepass 2 (LDS transpose, coalesced both sides) ----------
// x NCHW f32 -> xb[n][h][g'] bf16, g' = iw*16 + (c16 ^ (iw&7)).
__global__ __launch_bounds__(256) void repack_x(const float* __restrict__ x,
                                                unsigned short* __restrict__ xb) {
  __shared__ float xt[56][129];
  const int h = blockIdx.x;       // 0..55
  const int n = blockIdx.y;       // 0..31
  const float* src = x + (size_t)n * CIN * (H * W) + h * W;
  #pragma unroll
  for (int r = 0; r < 28; ++r) {
    int idx = r * 256 + threadIdx.x;
    int ci = idx / 56, iw = idx % 56;
    xt[iw][ci] = src[ci * (H * W) + iw];
  }
  __syncthreads();
  unsigned short* dst = xb + ((size_t)n * H + h) * 896 * 8;
  #pragma unroll
  for (int r = 0; r < 4; ++r) {
    int g = r * 256 + threadIdx.x;
    if (g < 896) {
      int iw = g >> 4, c16 = g & 15;
      short8 v;
      #pragma unroll
      for (int j = 0; j < 8; ++j)
        v[j] = (short)f2bf(xt[iw][c16 * 8 + j]);
      int gp = iw * 16 + (c16 ^ (iw & 7));
      *reinterpret_cast<short8*>(&dst[gp * 8]) = v;
    }
  }
}

// ---------- main conv: per-wave PRIVATE LDS A-ring, counted vmcnt, ZERO barriers ----
// 8 waves = 4 co-groups x 2 rows. Each wave DMAs its own 4KB A-slice per k-step
// into a private 3-slot ring (only this wave reads it -> no s_barrier needed;
// the only wait is the wave's own counted vmcnt, 2 tiles in flight).
__global__ __launch_bounds__(512, 2) void conv5(
    const unsigned short* __restrict__ xb, const unsigned short* __restrict__ w3,
    const float* __restrict__ bias, float* __restrict__ out) {
  __shared__ alignas(16) unsigned short xs[3744 * 8];     // 59,904 B
  __shared__ alignas(16) unsigned short aw[8][3][2048];   // 8 waves x 3 slots x 4KB = 98,304 B

  // XCD-bijective swizzle: 864 % 8 == 0
  const int f = blockIdx.x;
  const int swz = (f & 7) * 108 + (f >> 3);
  const int ohp = swz % 27;
  const int n   = swz / 27;
  const int oh0 = ohp * 2;
  const int tid = threadIdx.x;
  const int wid  = tid >> 6;
  const int lane = tid & 63;

  const int wm   = wid >> 1;       // co group (0..3)
  const int wn   = wid & 1;        // output row within the pair
  const int l16  = lane & 15;
  const int cig  = lane >> 4;      // 0..3
  const int co_base = wm * 64;
  const int oh = oh0 + wn;
  const int rowd = cig * 4;

  // ---- bias preload (drained in prologue; keeps loop vmem = DMA only) ----
  float bv[4][4];
  #pragma unroll
  for (int m = 0; m < 4; ++m)
    #pragma unroll
    for (int reg = 0; reg < 4; ++reg)
      bv[m][reg] = bias[co_base + m * 16 + rowd + reg];

  // ---- stage x rows (7 wave-issues per wave) ----
  {
    const unsigned short* src = xb + ((size_t)n * H + oh0) * 896 * 8;
    #pragma unroll
    for (int i = 0; i < 7; ++i) {
      int idx = (wid * 7 + i) * 64;
      __builtin_amdgcn_global_load_lds(
          (glb_u32*)(src + (size_t)(idx + lane) * 8),
          (lds_u32*)(&xs[idx * 8]), 16, 0, 0);
    }
  }

  // per-wave A-slice DMA for k-step t: 4 chunks of 1KB (g = 0..3), private slot
#define ASTAGE(t)                                                                \
  {                                                                              \
    unsigned short* adst_ = &aw[wid][(t) % 3][0];                                \
    const unsigned short* asrc_ =                                                \
        w3 + ((size_t)(t) * 4 * COUT + co_base) * 8 + (size_t)lane * 8;          \
    __builtin_amdgcn_global_load_lds((glb_u32*)(asrc_),                          \
                                     (lds_u32*)(adst_), 16, 0, 0);               \
    __builtin_amdgcn_global_load_lds((glb_u32*)(asrc_ + COUT * 8),               \
                                     (lds_u32*)(adst_ + 512), 16, 0, 0);         \
    __builtin_amdgcn_global_load_lds((glb_u32*)(asrc_ + 2 * COUT * 8),           \
                                     (lds_u32*)(adst_ + 1024), 16, 0, 0);        \
    __builtin_amdgcn_global_load_lds((glb_u32*)(asrc_ + 3 * COUT * 8),           \
                                     (lds_u32*)(adst_ + 1536), 16, 0, 0);        \
  }

  ASTAGE(0);
  ASTAGE(1);
  // outstanding: bias(16) + xs(7) + A0(4) + A1(4). Wait until only A1 remains:
  // bias, xs, A0 complete (in-order retirement). One barrier for xs visibility.
  asm volatile("s_waitcnt vmcnt(4)" ::: "memory");
  __builtin_amdgcn_s_barrier();
  __builtin_amdgcn_sched_barrier(0);

  // per-wave B addressing
  const int bwn = wn * 896 * 8;
  int ib[3], x7[3];
  #pragma unroll
  for (int kw = 0; kw < 3; ++kw) {
    ib[kw] = (l16 + kw) * 128;
    x7[kw] = (l16 + kw) & 7;
  }
  const int aoff = cig * 512 + l16 * 8;

  floatx4 acc[4][4];
  #pragma unroll
  for (int m = 0; m < 4; ++m)
    #pragma unroll
    for (int nr = 0; nr < 4; ++nr)
      acc[m][nr] = (floatx4){0.f, 0.f, 0.f, 0.f};

  #pragma unroll
  for (int t = 0; t < 36; ++t) {
    if (t + 2 < 36) ASTAGE(t + 2);   // keep 2 tiles in flight

    // counted wait on THIS wave's own DMAs: A(t) landed, A(t+1)/A(t+2) in flight
    if (t < 34)       asm volatile("s_waitcnt vmcnt(8)" ::: "memory");
    else if (t == 34) asm volatile("s_waitcnt vmcnt(4)" ::: "memory");
    else              asm volatile("s_waitcnt vmcnt(0)" ::: "memory");
    __builtin_amdgcn_sched_barrier(0);

    const int kh = t / 12, ch = (t / 3) & 3, kw = t % 3;
    short8 a[4], b[4];
    const unsigned short* ab = &aw[wid][t % 3][aoff];
    a[0] = *reinterpret_cast<const short8*>(ab);
    a[1] = *reinterpret_cast<const short8*>(ab + 128);
    a[2] = *reinterpret_cast<const short8*>(ab + 256);
    a[3] = *reinterpret_cast<const short8*>(ab + 384);
    const int c16x = (ch * 4 + cig) ^ x7[kw];
    const int boff = bwn + kh * (896 * 8) + ib[kw] + c16x * 8;
    b[0] = *reinterpret_cast<const short8*>(&xs[boff]);
    b[1] = *reinterpret_cast<const short8*>(&xs[boff + 2048]);
    b[2] = *reinterpret_cast<const short8*>(&xs[boff + 4096]);
    b[3] = *reinterpret_cast<const short8*>(&xs[boff + 6144]);

    __builtin_amdgcn_s_setprio(1);
    #pragma unroll
    for (int m = 0; m < 4; ++m)
      #pragma unroll
      for (int nr = 0; nr < 4; ++nr)
        acc[m][nr] = __builtin_amdgcn_mfma_f32_16x16x32_bf16(a[m], b[nr], acc[m][nr], 0, 0, 0);
    __builtin_amdgcn_s_setprio(0);
  }
#undef ASTAGE

  // ---- epilogue: C/D layout col=lane&15, row=(lane>>4)*4+reg ----
  #pragma unroll
  for (int m = 0; m < 4; ++m) {
    #pragma unroll
    for (int reg = 0; reg < 4; ++reg) {
      int co = co_base + m * 16 + rowd + reg;
      float* op = out + (((size_t)n * COUT + co) * OH + oh) * OW;
      #pragma unroll
      for (int nr = 0; nr < 4; ++nr) {
        int ow = nr * 16 + l16;
        if (ow < OW) op[ow] = acc[m][nr][reg] + bv[m][reg];
      }
    }
  }
}

// ================== fallback path (ws too small): round-2 kernel ==================
#define CSTR 136
#define IWP 66

__global__ void repack_w_fb(const float* __restrict__ w, unsigned short* __restrict__ w2) {
  int idx = blockIdx.x * 256 + threadIdx.x;
  if (idx >= COUT * CIN * 9) return;
  int kw = idx % 3, t1 = idx / 3;
  int kh = t1 % 3, t2 = t1 / 3;
  int ci = t2 % CIN;
  int co = t2 / CIN;
  int c8 = ci >> 3, j = ci & 7;
  w2[((((kh * 3 + kw) * 16 + c8) * COUT + co) * 8) + j] = f2bf(w[idx]);
}

__global__ __launch_bounds__(512, 4) void conv_fb(
    const float* __restrict__ x, const unsigned short* __restrict__ w2,
    const float* __restrict__ bias, float* __restrict__ out) {
  __shared__ alignas(16) unsigned short xsf[4 * IWP * CSTR];

  const int ohp = blockIdx.x;
  const int n   = blockIdx.y;
  const int oh0 = ohp * 2;
  const int tid = threadIdx.x;

  {
    short8 zz = {0, 0, 0, 0, 0, 0, 0, 0};
    for (int i = tid; i < 4 * 10 * 17; i += 512) {
      int r = i / 170, rem = i % 170;
      int iw = 56 + rem / 17, g = rem % 17;
      *reinterpret_cast<short8*>(&xsf[(r * IWP + iw) * CSTR + g * 8]) = zz;
    }
  }
  for (int s = tid; s < 3584; s += 512) {
    int iw = s % 56;
    int t  = s / 56;
    int c8 = t & 15, r = t >> 4;
    const float* xp = x + (size_t)n * CIN * (H * W) + (oh0 + r) * W + iw;
    short8 v;
    #pragma unroll
    for (int j = 0; j < 8; ++j)
      v[j] = (short)f2bf(xp[(size_t)(c8 * 8 + j) * (H * W)]);
    *reinterpret_cast<short8*>(&xsf[(r * IWP + iw) * CSTR + c8 * 8]) = v;
  }
  __syncthreads();

  const int wid  = tid >> 6;
  const int lane = tid & 63;
  const int wm   = wid >> 1;
  const int wn   = wid & 1;
  const int l16  = lane & 15;
  const int cig  = lane >> 4;

  const int co_base = wm * 64;
  const int oh = oh0 + wn;

  floatx4 acc[4][4];
  #pragma unroll
  for (int m = 0; m < 4; ++m)
    #pragma unroll
    for (int nr = 0; nr < 4; ++nr)
      acc[m][nr] = (floatx4){0.f, 0.f, 0.f, 0.f};

  for (int kh = 0; kh < 3; ++kh) {
    const int row = wn + kh;
    #pragma unroll
    for (int ch = 0; ch < 4; ++ch) {
      const int bbase = (row * IWP + l16) * CSTR + ch * 32 + cig * 8;
      #pragma unroll
      for (int kw = 0; kw < 3; ++kw) {
        const unsigned short* wp =
            w2 + ((size_t)(((kh * 3 + kw) * 16 + (ch * 4 + cig)) * COUT + co_base + l16)) * 8;
        short8 a[4];
        #pragma unroll
        for (int m = 0; m < 4; ++m)
          a[m] = *reinterpret_cast<const short8*>(wp + m * 16 * 8);
        short8 b[4];
        #pragma unroll
        for (int nr = 0; nr < 4; ++nr)
          b[nr] = *reinterpret_cast<const short8*>(&xsf[bbase + (nr * 16 + kw) * CSTR]);
        #pragma unroll
        for (int m = 0; m < 4; ++m)
          #pragma unroll
          for (int nr = 0; nr < 4; ++nr)
            acc[m][nr] = __builtin_amdgcn_mfma_f32_16x16x32_bf16(a[m], b[nr], acc[m][nr], 0, 0, 0);
      }
    }
  }

  const int rowd = cig * 4;
  #pragma unroll
  for (int m = 0; m < 4; ++m) {
    #pragma unroll
    for (int reg = 0; reg < 4; ++reg) {
      int co = co_base + m * 16 + rowd + reg;
      float bvv = bias[co];
      float* op = out + (((size_t)n * COUT + co) * OH + oh) * OW;
      #pragma unroll
      for (int nr = 0; nr < 4; ++nr) {
        int ow = nr * 16 + l16;
        if (ow < OW) op[ow] = acc[m][nr][reg] + bvv;
      }
    }
  }
}

extern "C" void kernel_launch(void* const* d_in, const int* in_sizes, int n_in,
                              void* d_out, int out_size, void* d_ws, size_t ws_size,
                              hipStream_t stream) {
  (void)in_sizes; (void)n_in; (void)out_size;
  const float* x    = (const float*)d_in[0];
  const float* w    = (const float*)d_in[1];
  const float* bias = (const float*)d_in[2];
  float* out = (float*)d_out;

  const size_t W3_BYTES = (size_t)36 * 4 * COUT * 8 * 2;            // 589,824
  const size_t XB_BYTES = (size_t)32 * H * 896 * 8 * 2;             // 25,690,112
  unsigned short* wrep = (unsigned short*)d_ws;

  if (ws_size >= W3_BYTES + XB_BYTES) {
    unsigned short* xbuf = (unsigned short*)((char*)d_ws + W3_BYTES);
    repack_w<<<dim3((COUT * CIN * 9 + 255) / 256), dim3(256), 0, stream>>>(w, wrep);
    repack_x<<<dim3(56, 32), dim3(256), 0, stream>>>(x, xbuf);
    conv5<<<dim3(864), dim3(512), 0, stream>>>(xbuf, wrep, bias, out);
  } else {
    repack_w_fb<<<dim3((COUT * CIN * 9 + 255) / 256), dim3(256), 0, stream>>>(w, wrep);
    conv_fb<<<dim3(27, 32), dim3(512), 0, stream>>>(x, wrep, bias, out);
  }
}

// Round 13
// 93.043 us; speedup vs baseline: 1.4872x; 1.2186x over previous
//
#include <hip/hip_runtime.h>
#include <hip/hip_bf16.h>

#define CIN 128
#define COUT 256
#define H 56
#define W 56
#define OH 54
#define OW 54

typedef __attribute__((ext_vector_type(8))) short short8;
typedef __attribute__((ext_vector_type(4))) float floatx4;

typedef __attribute__((address_space(3))) unsigned int  lds_u32;
typedef const __attribute__((address_space(1))) unsigned int glb_u32;

static __device__ __forceinline__ unsigned short f2bf(float f) {
  unsigned int u = __builtin_bit_cast(unsigned int, f);
  u += 0x7fffu + ((u >> 16) & 1u);   // RNE
  return (unsigned short)(u >> 16);
}

// ---------- prepass 1: w[co][ci][kh][kw] f32 -> w2[k16][co][8] bf16 ----------
// k16 = (kh*3+kw)*16 + c8 ; ci = c8*8 + j
__global__ void repack_w(const float* __restrict__ w, unsigned short* __restrict__ w2) {
  int idx = blockIdx.x * 256 + threadIdx.x;
  if (idx >= COUT * CIN * 9) return;
  int kw = idx % 3, t1 = idx / 3;
  int kh = t1 % 3, t2 = t1 / 3;
  int ci = t2 % CIN;
  int co = t2 / CIN;
  int c8 = ci >> 3, j = ci & 7;
  w2[((((kh * 3 + kw) * 16 + c8) * COUT + co) * 8) + j] = f2bf(w[idx]);
}

// ---------- prepass 2 (LDS transpose, coalesced both sides) ----------
// x NCHW f32 -> xb[n][h][g'] bf16, g' = iw*16 + (c16 ^ (iw&7)).
__global__ __launch_bounds__(256) void repack_x(const float* __restrict__ x,
                                                unsigned short* __restrict__ xb) {
  __shared__ float xt[56][129];
  const int h = blockIdx.x;       // 0..55
  const int n = blockIdx.y;       // 0..31
  const float* src = x + (size_t)n * CIN * (H * W) + h * W;
  #pragma unroll
  for (int r = 0; r < 28; ++r) {
    int idx = r * 256 + threadIdx.x;
    int ci = idx / 56, iw = idx % 56;
    xt[iw][ci] = src[ci * (H * W) + iw];
  }
  __syncthreads();
  unsigned short* dst = xb + ((size_t)n * H + h) * 896 * 8;
  #pragma unroll
  for (int r = 0; r < 4; ++r) {
    int g = r * 256 + threadIdx.x;
    if (g < 896) {
      int iw = g >> 4, c16 = g & 15;
      short8 v;
      #pragma unroll
      for (int j = 0; j < 8; ++j)
        v[j] = (short)f2bf(xt[iw][c16 * 8 + j]);
      int gp = iw * 16 + (c16 ^ (iw & 7));
      *reinterpret_cast<short8*>(&dst[gp * 8]) = v;
    }
  }
}

// ---------- main conv: LEAN blocks for TLP ----------
// 256 threads = 4 waves = 4 co-groups; block computes 1 output row x 256 co.
// LDS 46 KB -> 3 blocks/CU = 12 waves/CU = 3 waves/SIMD: independent blocks
// desynchronize, so other waves' MFMA covers each wave's A-L2-latency chain.
__global__ __launch_bounds__(256, 3) void conv6(
    const unsigned short* __restrict__ xb, const unsigned short* __restrict__ w2,
    const float* __restrict__ bias, float* __restrict__ out) {
  __shared__ alignas(16) unsigned short xs[2880 * 8];   // 46,080 B (3 rows + pad)

  // XCD-bijective swizzle: 1728 % 8 == 0; 216 consecutive row-blocks per XCD
  const int f = blockIdx.x;
  const int swz = (f & 7) * 216 + (f >> 3);
  const int oh = swz % 54;
  const int n  = swz / 54;
  const int tid  = threadIdx.x;
  const int wid  = tid >> 6;       // co group (0..3)
  const int lane = tid & 63;
  const int l16  = lane & 15;
  const int cig  = lane >> 4;      // 0..3
  const int co_base = wid * 64;
  const int rowd = cig * 4;

  // ---- bias preload ----
  float bv[4][4];
  #pragma unroll
  for (int m = 0; m < 4; ++m)
    #pragma unroll
    for (int reg = 0; reg < 4; ++reg)
      bv[m][reg] = bias[co_base + m * 16 + rowd + reg];

  // ---- stage rows oh..oh+2 (2688 granules) + 192-granule pad: 45 issues ----
  // Source clamped at xb end; clamped/garbage granules feed only ow>=54
  // columns, whose stores are masked (MFMA columns are independent).
  {
    const size_t gbase = ((size_t)n * H + oh) * 896;
    const size_t gmax  = (size_t)32 * H * 896 - 64;   // last valid 64-granule chunk
    #pragma unroll
    for (int i = 0; i < 12; ++i) {
      int c = i * 4 + wid;
      if (c < 45) {
        size_t sg = gbase + (size_t)c * 64;
        if (sg > gmax) sg = gmax;
        __builtin_amdgcn_global_load_lds(
            (glb_u32*)(xb + (sg + lane) * 8),
            (lds_u32*)(&xs[(size_t)c * 64 * 8]), 16, 0, 0);
      }
    }
  }
  asm volatile("s_waitcnt vmcnt(0)" ::: "memory");
  __syncthreads();

  floatx4 acc[4][4];
  #pragma unroll
  for (int m = 0; m < 4; ++m)
    #pragma unroll
    for (int nr = 0; nr < 4; ++nr)
      acc[m][nr] = (floatx4){0.f, 0.f, 0.f, 0.f};

  #pragma unroll
  for (int s = 0; s < 36; ++s) {
    const int kh = s / 12, ch = (s / 3) & 3, kw = s % 3;
    // A fragments: direct from global (L2-resident repacked weights)
    const unsigned short* wp =
        w2 + ((size_t)(((kh * 3 + kw) * 16 + (ch * 4 + cig)) * COUT + co_base + l16)) * 8;
    short8 a[4];
    #pragma unroll
    for (int m = 0; m < 4; ++m)
      a[m] = *reinterpret_cast<const short8*>(wp + m * 128);
    // B fragments: swizzled LDS reads from the 3-row slab
    const int iwl = l16 + kw;
    const int c16x = (ch * 4 + cig) ^ (iwl & 7);
    const int boff = (kh * 896 + iwl * 16 + c16x) * 8;
    short8 b[4];
    #pragma unroll
    for (int nr = 0; nr < 4; ++nr)
      b[nr] = *reinterpret_cast<const short8*>(&xs[boff + nr * 2048]);

    __builtin_amdgcn_s_setprio(1);
    #pragma unroll
    for (int m = 0; m < 4; ++m)
      #pragma unroll
      for (int nr = 0; nr < 4; ++nr)
        acc[m][nr] = __builtin_amdgcn_mfma_f32_16x16x32_bf16(a[m], b[nr], acc[m][nr], 0, 0, 0);
    __builtin_amdgcn_s_setprio(0);
  }

  // ---- epilogue: C/D layout col=lane&15, row=(lane>>4)*4+reg ----
  #pragma unroll
  for (int m = 0; m < 4; ++m) {
    #pragma unroll
    for (int reg = 0; reg < 4; ++reg) {
      int co = co_base + m * 16 + rowd + reg;
      float* op = out + (((size_t)n * COUT + co) * OH + oh) * OW;
      #pragma unroll
      for (int nr = 0; nr < 4; ++nr) {
        int ow = nr * 16 + l16;
        if (ow < OW) op[ow] = acc[m][nr][reg] + bv[m][reg];
      }
    }
  }
}

// ================== fallback path (ws too small): round-2 kernel ==================
#define CSTR 136
#define IWP 66

__global__ __launch_bounds__(512, 4) void conv_fb(
    const float* __restrict__ x, const unsigned short* __restrict__ w2,
    const float* __restrict__ bias, float* __restrict__ out) {
  __shared__ alignas(16) unsigned short xsf[4 * IWP * CSTR];

  const int ohp = blockIdx.x;
  const int n   = blockIdx.y;
  const int oh0 = ohp * 2;
  const int tid = threadIdx.x;

  {
    short8 zz = {0, 0, 0, 0, 0, 0, 0, 0};
    for (int i = tid; i < 4 * 10 * 17; i += 512) {
      int r = i / 170, rem = i % 170;
      int iw = 56 + rem / 17, g = rem % 17;
      *reinterpret_cast<short8*>(&xsf[(r * IWP + iw) * CSTR + g * 8]) = zz;
    }
  }
  for (int s = tid; s < 3584; s += 512) {
    int iw = s % 56;
    int t  = s / 56;
    int c8 = t & 15, r = t >> 4;
    const float* xp = x + (size_t)n * CIN * (H * W) + (oh0 + r) * W + iw;
    short8 v;
    #pragma unroll
    for (int j = 0; j < 8; ++j)
      v[j] = (short)f2bf(xp[(size_t)(c8 * 8 + j) * (H * W)]);
    *reinterpret_cast<short8*>(&xsf[(r * IWP + iw) * CSTR + c8 * 8]) = v;
  }
  __syncthreads();

  const int wid  = tid >> 6;
  const int lane = tid & 63;
  const int wm   = wid >> 1;
  const int wn   = wid & 1;
  const int l16  = lane & 15;
  const int cig  = lane >> 4;

  const int co_base = wm * 64;
  const int oh = oh0 + wn;

  floatx4 acc[4][4];
  #pragma unroll
  for (int m = 0; m < 4; ++m)
    #pragma unroll
    for (int nr = 0; nr < 4; ++nr)
      acc[m][nr] = (floatx4){0.f, 0.f, 0.f, 0.f};

  for (int kh = 0; kh < 3; ++kh) {
    const int row = wn + kh;
    #pragma unroll
    for (int ch = 0; ch < 4; ++ch) {
      const int bbase = (row * IWP + l16) * CSTR + ch * 32 + cig * 8;
      #pragma unroll
      for (int kw = 0; kw < 3; ++kw) {
        const unsigned short* wp =
            w2 + ((size_t)(((kh * 3 + kw) * 16 + (ch * 4 + cig)) * COUT + co_base + l16)) * 8;
        short8 a[4];
        #pragma unroll
        for (int m = 0; m < 4; ++m)
          a[m] = *reinterpret_cast<const short8*>(wp + m * 16 * 8);
        short8 b[4];
        #pragma unroll
        for (int nr = 0; nr < 4; ++nr)
          b[nr] = *reinterpret_cast<const short8*>(&xsf[bbase + (nr * 16 + kw) * CSTR]);
        #pragma unroll
        for (int m = 0; m < 4; ++m)
          #pragma unroll
          for (int nr = 0; nr < 4; ++nr)
            acc[m][nr] = __builtin_amdgcn_mfma_f32_16x16x32_bf16(a[m], b[nr], acc[m][nr], 0, 0, 0);
      }
    }
  }

  const int rowd = cig * 4;
  #pragma unroll
  for (int m = 0; m < 4; ++m) {
    #pragma unroll
    for (int reg = 0; reg < 4; ++reg) {
      int co = co_base + m * 16 + rowd + reg;
      float bvv = bias[co];
      float* op = out + (((size_t)n * COUT + co) * OH + oh) * OW;
      #pragma unroll
      for (int nr = 0; nr < 4; ++nr) {
        int ow = nr * 16 + l16;
        if (ow < OW) op[ow] = acc[m][nr][reg] + bvv;
      }
    }
  }
}

extern "C" void kernel_launch(void* const* d_in, const int* in_sizes, int n_in,
                              void* d_out, int out_size, void* d_ws, size_t ws_size,
                              hipStream_t stream) {
  (void)in_sizes; (void)n_in; (void)out_size;
  const float* x    = (const float*)d_in[0];
  const float* w    = (const float*)d_in[1];
  const float* bias = (const float*)d_in[2];
  float* out = (float*)d_out;

  const size_t W2_BYTES = (size_t)9 * 16 * COUT * 8 * 2;            // 589,824
  const size_t XB_BYTES = (size_t)32 * H * 896 * 8 * 2;             // 25,690,112
  unsigned short* w2 = (unsigned short*)d_ws;

  repack_w<<<dim3((COUT * CIN * 9 + 255) / 256), dim3(256), 0, stream>>>(w, w2);

  if (ws_size >= W2_BYTES + XB_BYTES) {
    unsigned short* xb = (unsigned short*)((char*)d_ws + W2_BYTES);
    repack_x<<<dim3(56, 32), dim3(256), 0, stream>>>(x, xb);
    conv6<<<dim3(1728), dim3(256), 0, stream>>>(xb, w2, bias, out);
  } else {
    conv_fb<<<dim3(27, 32), dim3(512), 0, stream>>>(x, w2, bias, out);
  }
}